// Round 1
// baseline (20729.456 us; speedup 1.0000x reference)
//
#include <hip/hip_runtime.h>
#include <hip/hip_bf16.h>
#include <math.h>

#define DIMX 768
#define DEPTH 4
#define NHEADS 12
#define FFDIM 3072
#define BBATCH 2
#define TSEQ 2048
#define DKH 64
#define MROWS (BBATCH * TSEQ)   // 4096

// ---------------------------------------------------------------------------
// Positional encoding add: h = x + PE
// ---------------------------------------------------------------------------
__global__ __launch_bounds__(256) void pe_add_kernel(const float* __restrict__ x,
                                                     float* __restrict__ h) {
    int idx = blockIdx.x * 256 + threadIdx.x;
    int total = MROWS * DIMX;
    if (idx >= total) return;
    int d = idx % DIMX;
    int t = (idx / DIMX) % TSEQ;
    int i2 = d & ~1;  // 2*(d/2)
    float div = expf((float)i2 * (-9.210340371976184f / (float)DIMX)); // -ln(10000)/D
    float ang = (float)t * div;
    float pe = (d & 1) ? cosf(ang) : sinf(ang);
    h[idx] = x[idx] + pe;
}

// ---------------------------------------------------------------------------
// fp32 GEMM: C[M,N] = A[M,K] @ W[K,N] + bias[N], optional ReLU
// 128x128 tile, BK=8, 256 threads, 8x8 per-thread register tile
// ---------------------------------------------------------------------------
template <int RELU>
__global__ __launch_bounds__(256) void gemm_kernel(const float* __restrict__ A,
                                                   const float* __restrict__ W,
                                                   const float* __restrict__ bias,
                                                   float* __restrict__ C,
                                                   int M, int N, int K) {
    __shared__ float As[8][128];   // [k][row]
    __shared__ float Bs[8][128];   // [k][col]

    const int tid = threadIdx.x;
    const int tx = tid & 15;   // 0..15 -> col group
    const int ty = tid >> 4;   // 0..15 -> row group
    const int r0 = blockIdx.y * 128;
    const int c0 = blockIdx.x * 128;

    float acc[8][8];
#pragma unroll
    for (int i = 0; i < 8; i++)
#pragma unroll
        for (int j = 0; j < 8; j++) acc[i][j] = 0.f;

    // A load: each thread one float4: row = tid/2 (0..127), k-half = (tid&1)*4
    const int arow = tid >> 1;
    const int ak4 = (tid & 1) * 4;
    // B load: each thread one float4: k = tid/32 (0..7), n = (tid&31)*4
    const int bk = tid >> 5;
    const int bn = (tid & 31) * 4;

    const float* Aptr = A + (size_t)(r0 + arow) * K + ak4;
    const float* Wptr = W + (size_t)bk * N + c0 + bn;

    for (int k0 = 0; k0 < K; k0 += 8) {
        float4 av = *(const float4*)(Aptr + k0);
        float4 bv = *(const float4*)(Wptr + (size_t)k0 * N);
        __syncthreads();  // previous iteration's reads done before overwrite
        As[ak4 + 0][arow] = av.x;
        As[ak4 + 1][arow] = av.y;
        As[ak4 + 2][arow] = av.z;
        As[ak4 + 3][arow] = av.w;
        *(float4*)&Bs[bk][bn] = bv;
        __syncthreads();
#pragma unroll
        for (int kk = 0; kk < 8; kk++) {
            float4 a0 = *(const float4*)&As[kk][ty * 8];
            float4 a1 = *(const float4*)&As[kk][ty * 8 + 4];
            float4 b0 = *(const float4*)&Bs[kk][tx * 8];
            float4 b1 = *(const float4*)&Bs[kk][tx * 8 + 4];
            float a[8] = {a0.x, a0.y, a0.z, a0.w, a1.x, a1.y, a1.z, a1.w};
            float b[8] = {b0.x, b0.y, b0.z, b0.w, b1.x, b1.y, b1.z, b1.w};
#pragma unroll
            for (int i = 0; i < 8; i++)
#pragma unroll
                for (int j = 0; j < 8; j++) acc[i][j] += a[i] * b[j];
        }
    }

#pragma unroll
    for (int i = 0; i < 8; i++) {
        int row = r0 + ty * 8 + i;
#pragma unroll
        for (int j = 0; j < 8; j += 4) {
            int col = c0 + tx * 8 + j;
            float4 o;
            o.x = acc[i][j + 0] + bias[col + 0];
            o.y = acc[i][j + 1] + bias[col + 1];
            o.z = acc[i][j + 2] + bias[col + 2];
            o.w = acc[i][j + 3] + bias[col + 3];
            if (RELU) {
                o.x = fmaxf(o.x, 0.f);
                o.y = fmaxf(o.y, 0.f);
                o.z = fmaxf(o.z, 0.f);
                o.w = fmaxf(o.w, 0.f);
            }
            *(float4*)&C[(size_t)row * N + col] = o;
        }
    }
}

// ---------------------------------------------------------------------------
// Causal attention, online softmax. qkv layout: [B,T,3,H,DK] row = 3*DIM.
// One wave per (b,h,t) row; 4 rows (same b,h) per block share K/V LDS tiles.
// ctx written as [B,T,H*DK] (row-major [B*T, 768]).
// ---------------------------------------------------------------------------
__global__ __launch_bounds__(256) void attn_kernel(const float* __restrict__ qkv,
                                                   float* __restrict__ ctx) {
    __shared__ float ks[64][64];
    __shared__ float vs[64][64];

    const int tid = threadIdx.x;
    const int lane = tid & 63;
    const int w = tid >> 6;          // wave 0..3
    const int rb = blockIdx.x * 4;   // first row of block; rows rb..rb+3 share (b,h)
    const int tbase = rb % TSEQ;
    const int t = tbase + w;
    const int bh = rb / TSEQ;
    const int b = bh / NHEADS;
    const int h = bh % NHEADS;

    const size_t qrow = ((size_t)b * TSEQ + t) * (3 * DIMX);
    const float q = qkv[qrow + h * DKH + lane];

    float m = -INFINITY, l = 0.f, acc = 0.f;
    const int smax = tbase + 3;  // max t in this block

    for (int s0 = 0; s0 <= smax; s0 += 64) {
        const int scount = min(64, smax + 1 - s0);
        __syncthreads();
        // stage K/V tile: 64 rows x 64 dims
#pragma unroll
        for (int i = 0; i < 4; i++) {
            int srow = (tid >> 4) + 16 * i;
            int d4 = (tid & 15) * 4;
            if (srow < scount) {
                size_t g = ((size_t)b * TSEQ + s0 + srow) * (3 * DIMX) + DIMX + h * DKH + d4;
                *(float4*)&ks[srow][d4] = *(const float4*)&qkv[g];
                *(float4*)&vs[srow][d4] = *(const float4*)&qkv[g + DIMX];
            }
        }
        __syncthreads();

        const int send = min(scount, t - s0 + 1);  // causal bound for this wave
        for (int s = 0; s < send; s++) {
            float sc = q * ks[s][lane];
#pragma unroll
            for (int off = 32; off; off >>= 1) sc += __shfl_xor(sc, off, 64);
            sc *= 0.125f;  // 1/sqrt(64)
            float mnew = fmaxf(m, sc);
            float corr = __expf(m - mnew);
            float p = __expf(sc - mnew);
            l = l * corr + p;
            acc = acc * corr + p * vs[s][lane];
            m = mnew;
        }
    }
    ctx[((size_t)b * TSEQ + t) * DIMX + h * DKH + lane] = acc / l;
}

// ---------------------------------------------------------------------------
// Fused residual + LayerNorm: out = LN(resid + y) * g + b    (row = 768)
// One block (256 threads) per row; 3 elements per thread. Safe in-place.
// ---------------------------------------------------------------------------
__global__ __launch_bounds__(256) void ln_kernel(const float* __restrict__ resid,
                                                 const float* __restrict__ y,
                                                 const float* __restrict__ g,
                                                 const float* __restrict__ bta,
                                                 float* __restrict__ out) {
    const int row = blockIdx.x;
    const int tid = threadIdx.x;
    __shared__ float red[4];

    float v[3];
#pragma unroll
    for (int i = 0; i < 3; i++) {
        int idx = tid + i * 256;
        size_t p = (size_t)row * DIMX + idx;
        v[i] = resid[p] + y[p];
    }
    float part = v[0] + v[1] + v[2];
#pragma unroll
    for (int off = 32; off; off >>= 1) part += __shfl_xor(part, off, 64);
    if ((tid & 63) == 0) red[tid >> 6] = part;
    __syncthreads();
    const float mean = (red[0] + red[1] + red[2] + red[3]) * (1.f / 768.f);

    float p2 = 0.f;
#pragma unroll
    for (int i = 0; i < 3; i++) {
        float d = v[i] - mean;
        p2 += d * d;
    }
#pragma unroll
    for (int off = 32; off; off >>= 1) p2 += __shfl_xor(p2, off, 64);
    __syncthreads();  // everyone done reading red before overwrite
    if ((tid & 63) == 0) red[tid >> 6] = p2;
    __syncthreads();
    const float var = (red[0] + red[1] + red[2] + red[3]) * (1.f / 768.f);
    const float inv = rsqrtf(var + 1e-5f);

#pragma unroll
    for (int i = 0; i < 3; i++) {
        int idx = tid + i * 256;
        out[(size_t)row * DIMX + idx] = (v[i] - mean) * inv * g[idx] + bta[idx];
    }
}

// ---------------------------------------------------------------------------
extern "C" void kernel_launch(void* const* d_in, const int* in_sizes, int n_in,
                              void* d_out, int out_size, void* d_ws, size_t ws_size,
                              hipStream_t stream) {
    (void)in_sizes; (void)n_in; (void)out_size; (void)ws_size;
    const float* x     = (const float*)d_in[0];
    // d_in[1] = mask (causal, hardcoded)
    const float* qkv_w = (const float*)d_in[2];
    const float* qkv_b = (const float*)d_in[3];
    const float* out_w = (const float*)d_in[4];
    const float* out_b = (const float*)d_in[5];
    const float* ff1_w = (const float*)d_in[6];
    const float* ff1_b = (const float*)d_in[7];
    const float* ff2_w = (const float*)d_in[8];
    const float* ff2_b = (const float*)d_in[9];
    const float* ln1_g = (const float*)d_in[10];
    const float* ln1_b = (const float*)d_in[11];
    const float* ln2_g = (const float*)d_in[12];
    const float* ln2_b = (const float*)d_in[13];

    float* h   = (float*)d_ws;                      // [4096, 768]
    float* qkv = h   + (size_t)MROWS * DIMX;        // [4096, 2304]
    float* ctx = qkv + (size_t)MROWS * 3 * DIMX;    // [4096, 768]
    float* y   = ctx + (size_t)MROWS * DIMX;        // [4096, 768]
    float* ff  = y   + (size_t)MROWS * DIMX;        // [4096, 3072]

    pe_add_kernel<<<(MROWS * DIMX + 255) / 256, 256, 0, stream>>>(x, h);

    for (int lyr = 0; lyr < DEPTH; ++lyr) {
        gemm_kernel<0><<<dim3(3 * DIMX / 128, MROWS / 128), 256, 0, stream>>>(
            h, qkv_w + (size_t)lyr * DIMX * 3 * DIMX, qkv_b + (size_t)lyr * 3 * DIMX,
            qkv, MROWS, 3 * DIMX, DIMX);
        attn_kernel<<<BBATCH * NHEADS * TSEQ / 4, 256, 0, stream>>>(qkv, ctx);
        gemm_kernel<0><<<dim3(DIMX / 128, MROWS / 128), 256, 0, stream>>>(
            ctx, out_w + (size_t)lyr * DIMX * DIMX, out_b + (size_t)lyr * DIMX,
            y, MROWS, DIMX, DIMX);
        ln_kernel<<<MROWS, 256, 0, stream>>>(h, y, ln1_g + (size_t)lyr * DIMX,
                                             ln1_b + (size_t)lyr * DIMX, h);
        gemm_kernel<1><<<dim3(FFDIM / 128, MROWS / 128), 256, 0, stream>>>(
            h, ff1_w + (size_t)lyr * DIMX * FFDIM, ff1_b + (size_t)lyr * FFDIM,
            ff, MROWS, FFDIM, DIMX);
        gemm_kernel<0><<<dim3(DIMX / 128, MROWS / 128), 256, 0, stream>>>(
            ff, ff2_w + (size_t)lyr * FFDIM * DIMX, ff2_b + (size_t)lyr * DIMX,
            y, MROWS, DIMX, FFDIM);
        ln_kernel<<<MROWS, 256, 0, stream>>>(h, y, ln2_g + (size_t)lyr * DIMX,
                                             ln2_b + (size_t)lyr * DIMX, h);
    }
    hipMemcpyAsync(d_out, h, (size_t)MROWS * DIMX * sizeof(float),
                   hipMemcpyDeviceToDevice, stream);
}

// Round 2
// 7758.183 us; speedup vs baseline: 2.6719x; 2.6719x over previous
//
#include <hip/hip_runtime.h>
#include <hip/hip_bf16.h>
#include <math.h>

#define DIMX 768
#define DEPTH 4
#define NHEADS 12
#define FFDIM 3072
#define BBATCH 2
#define TSEQ 2048
#define DKH 64
#define MROWS (BBATCH * TSEQ)   // 4096

// ---------------------------------------------------------------------------
// Positional encoding add: h = x + PE
// ---------------------------------------------------------------------------
__global__ __launch_bounds__(256) void pe_add_kernel(const float* __restrict__ x,
                                                     float* __restrict__ h) {
    int idx = blockIdx.x * 256 + threadIdx.x;
    int total = MROWS * DIMX;
    if (idx >= total) return;
    int d = idx % DIMX;
    int t = (idx / DIMX) % TSEQ;
    int i2 = d & ~1;  // 2*(d/2)
    float div = expf((float)i2 * (-9.210340371976184f / (float)DIMX)); // -ln(10000)/D
    float ang = (float)t * div;
    float pe = (d & 1) ? cosf(ang) : sinf(ang);
    h[idx] = x[idx] + pe;
}

// ---------------------------------------------------------------------------
// fp32 GEMM: C[M,N] = A[M,K] @ W[K,N] + bias[N], optional ReLU
// 128x128 tile, BK=8, 256 threads, 8x8 per-thread register tile
// ---------------------------------------------------------------------------
template <int RELU>
__global__ __launch_bounds__(256) void gemm_kernel(const float* __restrict__ A,
                                                   const float* __restrict__ W,
                                                   const float* __restrict__ bias,
                                                   float* __restrict__ C,
                                                   int M, int N, int K) {
    __shared__ float As[8][128];   // [k][row]
    __shared__ float Bs[8][128];   // [k][col]

    const int tid = threadIdx.x;
    const int tx = tid & 15;   // 0..15 -> col group
    const int ty = tid >> 4;   // 0..15 -> row group
    const int r0 = blockIdx.y * 128;
    const int c0 = blockIdx.x * 128;

    float acc[8][8];
#pragma unroll
    for (int i = 0; i < 8; i++)
#pragma unroll
        for (int j = 0; j < 8; j++) acc[i][j] = 0.f;

    const int arow = tid >> 1;
    const int ak4 = (tid & 1) * 4;
    const int bk = tid >> 5;
    const int bn = (tid & 31) * 4;

    const float* Aptr = A + (size_t)(r0 + arow) * K + ak4;
    const float* Wptr = W + (size_t)bk * N + c0 + bn;

    for (int k0 = 0; k0 < K; k0 += 8) {
        float4 av = *(const float4*)(Aptr + k0);
        float4 bv = *(const float4*)(Wptr + (size_t)k0 * N);
        __syncthreads();
        As[ak4 + 0][arow] = av.x;
        As[ak4 + 1][arow] = av.y;
        As[ak4 + 2][arow] = av.z;
        As[ak4 + 3][arow] = av.w;
        *(float4*)&Bs[bk][bn] = bv;
        __syncthreads();
#pragma unroll
        for (int kk = 0; kk < 8; kk++) {
            float4 a0 = *(const float4*)&As[kk][ty * 8];
            float4 a1 = *(const float4*)&As[kk][ty * 8 + 4];
            float4 b0 = *(const float4*)&Bs[kk][tx * 8];
            float4 b1 = *(const float4*)&Bs[kk][tx * 8 + 4];
            float a[8] = {a0.x, a0.y, a0.z, a0.w, a1.x, a1.y, a1.z, a1.w};
            float b[8] = {b0.x, b0.y, b0.z, b0.w, b1.x, b1.y, b1.z, b1.w};
#pragma unroll
            for (int i = 0; i < 8; i++)
#pragma unroll
                for (int j = 0; j < 8; j++) acc[i][j] += a[i] * b[j];
        }
    }

#pragma unroll
    for (int i = 0; i < 8; i++) {
        int row = r0 + ty * 8 + i;
#pragma unroll
        for (int j = 0; j < 8; j += 4) {
            int col = c0 + tx * 8 + j;
            float4 o;
            o.x = acc[i][j + 0] + bias[col + 0];
            o.y = acc[i][j + 1] + bias[col + 1];
            o.z = acc[i][j + 2] + bias[col + 2];
            o.w = acc[i][j + 3] + bias[col + 3];
            if (RELU) {
                o.x = fmaxf(o.x, 0.f);
                o.y = fmaxf(o.y, 0.f);
                o.z = fmaxf(o.z, 0.f);
                o.w = fmaxf(o.w, 0.f);
            }
            *(float4*)&C[(size_t)row * N + col] = o;
        }
    }
}

// ---------------------------------------------------------------------------
// Causal attention, lane-parallel (lane = key index s within tile).
// qkv layout: [B,T,3,H,DK] row = 3*DIM. One wave per (b,h,t); 4 rows (same
// b,h) per block share 64x64 K/V LDS tiles (fp32, XOR-swizzled float4 slots).
// Each lane: full 64-d dot product for its s; p stays lane-local; per-lane
// 64-float accumulator; final 63-step butterfly transpose-reduce (d = lane).
// ---------------------------------------------------------------------------
__global__ __launch_bounds__(256) void attn_kernel(const float* __restrict__ qkv,
                                                   float* __restrict__ ctx) {
    __shared__ float4 ks4[16 * 64];   // 16 KB, slot = s*16 + (c ^ (s&7))
    __shared__ float4 vs4[16 * 64];   // 16 KB

    const int tid = threadIdx.x;
    const int lane = tid & 63;
    const int w = tid >> 6;          // wave 0..3
    const int rb = blockIdx.x * 4;
    const int tbase = rb % TSEQ;
    const int t = tbase + w;
    const int bh = rb / TSEQ;
    const int b = bh / NHEADS;
    const int h = bh % NHEADS;

    // q for this wave's row, broadcast into 16 float4 regs
    const float4* qptr = (const float4*)(qkv + ((size_t)b * TSEQ + t) * (3 * DIMX) + h * DKH);
    float4 q4[16];
#pragma unroll
    for (int i = 0; i < 16; i++) q4[i] = qptr[i];

    float acc[64];
#pragma unroll
    for (int i = 0; i < 64; i++) acc[i] = 0.f;
    float m = -INFINITY, lsum = 0.f;

    // swizzled float4 slots for this lane's row (reused every tile)
    int ridx[16];
#pragma unroll
    for (int c = 0; c < 16; c++) ridx[c] = lane * 16 + (c ^ (lane & 7));

    const int sc_ = tid & 15;   // staging col block
    const int sr_ = tid >> 4;   // staging row base (0..15)
    const int smax = tbase + 3;

    for (int s0 = 0; s0 <= smax; s0 += 64) {
        const int scount = min(64, smax + 1 - s0);
        __syncthreads();
#pragma unroll
        for (int i = 0; i < 4; i++) {
            int s = sr_ + i * 16;
            int slot = s * 16 + (sc_ ^ (s & 7));
            if (s < scount) {
                const float* kp = qkv + ((size_t)b * TSEQ + s0 + s) * (3 * DIMX)
                                + DIMX + h * DKH + sc_ * 4;
                ks4[slot] = *(const float4*)kp;
                vs4[slot] = *(const float4*)(kp + DIMX);
            } else {
                ks4[slot] = float4{0.f, 0.f, 0.f, 0.f};
                vs4[slot] = float4{0.f, 0.f, 0.f, 0.f};
            }
        }
        __syncthreads();

        // QK: each lane dots q with K[s0+lane]
        float sc = 0.f;
#pragma unroll
        for (int c = 0; c < 16; c++) {
            float4 kv = ks4[ridx[c]];
            sc += q4[c].x * kv.x + q4[c].y * kv.y + q4[c].z * kv.z + q4[c].w * kv.w;
        }
        sc *= 0.125f;                             // 1/sqrt(64)
        sc = (s0 + lane <= t) ? sc : -1e30f;      // causal mask

        float tmax = sc;
#pragma unroll
        for (int off = 32; off; off >>= 1) tmax = fmaxf(tmax, __shfl_xor(tmax, off));

        if (tmax > m + 8.f) {                     // defer-rescale (T13)
            float corr = __expf(m - tmax);
#pragma unroll
            for (int i = 0; i < 64; i++) acc[i] *= corr;
            lsum *= corr;
            m = tmax;
        }
        float p = __expf(sc - m);
        lsum += p;

        // PV: lane-local p times V[s0+lane][*]
#pragma unroll
        for (int c = 0; c < 16; c++) {
            float4 vv = vs4[ridx[c]];
            acc[c * 4 + 0] += p * vv.x;
            acc[c * 4 + 1] += p * vv.y;
            acc[c * 4 + 2] += p * vv.z;
            acc[c * 4 + 3] += p * vv.w;
        }
    }

    // reduce l across lanes
#pragma unroll
    for (int off = 32; off; off >>= 1) lsum += __shfl_xor(lsum, off);

    // butterfly transpose-reduce: after 6 steps lane l holds sum over all
    // lanes of acc[d = l]
#define RSTEP(OFF)                                                         \
    {                                                                      \
        bool hi = (lane & OFF) != 0;                                       \
        _Pragma("unroll")                                                  \
        for (int i = 0; i < OFF; i++) {                                    \
            float keep = hi ? acc[i + OFF] : acc[i];                       \
            float send = hi ? acc[i] : acc[i + OFF];                       \
            acc[i] = keep + __shfl_xor(send, OFF);                         \
        }                                                                  \
    }
    RSTEP(32) RSTEP(16) RSTEP(8) RSTEP(4) RSTEP(2) RSTEP(1)
#undef RSTEP

    ctx[((size_t)b * TSEQ + t) * DIMX + h * DKH + lane] = acc[0] / lsum;
}

// ---------------------------------------------------------------------------
// Fused residual + LayerNorm: out = LN(resid + y) * g + b    (row = 768)
// ---------------------------------------------------------------------------
__global__ __launch_bounds__(256) void ln_kernel(const float* __restrict__ resid,
                                                 const float* __restrict__ y,
                                                 const float* __restrict__ g,
                                                 const float* __restrict__ bta,
                                                 float* __restrict__ out) {
    const int row = blockIdx.x;
    const int tid = threadIdx.x;
    __shared__ float red[4];

    float v[3];
#pragma unroll
    for (int i = 0; i < 3; i++) {
        int idx = tid + i * 256;
        size_t p = (size_t)row * DIMX + idx;
        v[i] = resid[p] + y[p];
    }
    float part = v[0] + v[1] + v[2];
#pragma unroll
    for (int off = 32; off; off >>= 1) part += __shfl_xor(part, off, 64);
    if ((tid & 63) == 0) red[tid >> 6] = part;
    __syncthreads();
    const float mean = (red[0] + red[1] + red[2] + red[3]) * (1.f / 768.f);

    float p2 = 0.f;
#pragma unroll
    for (int i = 0; i < 3; i++) {
        float d = v[i] - mean;
        p2 += d * d;
    }
#pragma unroll
    for (int off = 32; off; off >>= 1) p2 += __shfl_xor(p2, off, 64);
    __syncthreads();
    if ((tid & 63) == 0) red[tid >> 6] = p2;
    __syncthreads();
    const float var = (red[0] + red[1] + red[2] + red[3]) * (1.f / 768.f);
    const float inv = rsqrtf(var + 1e-5f);

#pragma unroll
    for (int i = 0; i < 3; i++) {
        int idx = tid + i * 256;
        out[(size_t)row * DIMX + idx] = (v[i] - mean) * inv * g[idx] + bta[idx];
    }
}

// ---------------------------------------------------------------------------
extern "C" void kernel_launch(void* const* d_in, const int* in_sizes, int n_in,
                              void* d_out, int out_size, void* d_ws, size_t ws_size,
                              hipStream_t stream) {
    (void)in_sizes; (void)n_in; (void)out_size; (void)ws_size;
    const float* x     = (const float*)d_in[0];
    const float* qkv_w = (const float*)d_in[2];
    const float* qkv_b = (const float*)d_in[3];
    const float* out_w = (const float*)d_in[4];
    const float* out_b = (const float*)d_in[5];
    const float* ff1_w = (const float*)d_in[6];
    const float* ff1_b = (const float*)d_in[7];
    const float* ff2_w = (const float*)d_in[8];
    const float* ff2_b = (const float*)d_in[9];
    const float* ln1_g = (const float*)d_in[10];
    const float* ln1_b = (const float*)d_in[11];
    const float* ln2_g = (const float*)d_in[12];
    const float* ln2_b = (const float*)d_in[13];

    float* h   = (float*)d_ws;                      // [4096, 768]
    float* qkv = h   + (size_t)MROWS * DIMX;        // [4096, 2304]
    float* ctx = qkv + (size_t)MROWS * 3 * DIMX;    // [4096, 768]
    float* y   = ctx + (size_t)MROWS * DIMX;        // [4096, 768]
    float* ff  = y   + (size_t)MROWS * DIMX;        // [4096, 3072]

    pe_add_kernel<<<(MROWS * DIMX + 255) / 256, 256, 0, stream>>>(x, h);

    for (int lyr = 0; lyr < DEPTH; ++lyr) {
        gemm_kernel<0><<<dim3(3 * DIMX / 128, MROWS / 128), 256, 0, stream>>>(
            h, qkv_w + (size_t)lyr * DIMX * 3 * DIMX, qkv_b + (size_t)lyr * 3 * DIMX,
            qkv, MROWS, 3 * DIMX, DIMX);
        attn_kernel<<<BBATCH * NHEADS * TSEQ / 4, 256, 0, stream>>>(qkv, ctx);
        gemm_kernel<0><<<dim3(DIMX / 128, MROWS / 128), 256, 0, stream>>>(
            ctx, out_w + (size_t)lyr * DIMX * DIMX, out_b + (size_t)lyr * DIMX,
            y, MROWS, DIMX, DIMX);
        ln_kernel<<<MROWS, 256, 0, stream>>>(h, y, ln1_g + (size_t)lyr * DIMX,
                                             ln1_b + (size_t)lyr * DIMX, h);
        gemm_kernel<1><<<dim3(FFDIM / 128, MROWS / 128), 256, 0, stream>>>(
            h, ff1_w + (size_t)lyr * DIMX * FFDIM, ff1_b + (size_t)lyr * FFDIM,
            ff, MROWS, FFDIM, DIMX);
        gemm_kernel<0><<<dim3(DIMX / 128, MROWS / 128), 256, 0, stream>>>(
            ff, ff2_w + (size_t)lyr * FFDIM * DIMX, ff2_b + (size_t)lyr * DIMX,
            y, MROWS, DIMX, FFDIM);
        ln_kernel<<<MROWS, 256, 0, stream>>>(h, y, ln2_g + (size_t)lyr * DIMX,
                                             ln2_b + (size_t)lyr * DIMX, h);
    }
    hipMemcpyAsync(d_out, h, (size_t)MROWS * DIMX * sizeof(float),
                   hipMemcpyDeviceToDevice, stream);
}

// Round 4
// 4267.965 us; speedup vs baseline: 4.8570x; 1.8178x over previous
//
#include <hip/hip_runtime.h>
#include <hip/hip_bf16.h>
#include <math.h>

#define DIMX 768
#define DEPTH 4
#define NHEADS 12
#define FFDIM 3072
#define BBATCH 2
#define TSEQ 2048
#define DKH 64
#define MROWS (BBATCH * TSEQ)   // 4096

typedef __attribute__((ext_vector_type(8))) short short8;
typedef __attribute__((ext_vector_type(4))) float f32x4;

__device__ __forceinline__ short f2bf(float f) {
    union { float f; unsigned u; } v; v.f = f;
    unsigned r = v.u + 0x7fff + ((v.u >> 16) & 1);   // RNE
    return (short)(r >> 16);
}

// ---------------------------------------------------------------------------
// Positional encoding add: h = x + PE  (fp32 + bf16 outputs)
// ---------------------------------------------------------------------------
__global__ __launch_bounds__(256) void pe_add_kernel(const float* __restrict__ x,
                                                     float* __restrict__ h,
                                                     short* __restrict__ hb) {
    int idx = blockIdx.x * 256 + threadIdx.x;
    int total = MROWS * DIMX;
    if (idx >= total) return;
    int d = idx % DIMX;
    int t = (idx / DIMX) % TSEQ;
    int i2 = d & ~1;
    float div = expf((float)i2 * (-9.210340371976184f / (float)DIMX));
    float ang = (float)t * div;
    float pe = (d & 1) ? cosf(ang) : sinf(ang);
    float r = x[idx] + pe;
    h[idx] = r;
    hb[idx] = f2bf(r);
}

// ---------------------------------------------------------------------------
// Weight transpose + fp32->bf16: in [K][N] fp32  ->  out [N][K] bf16
// ---------------------------------------------------------------------------
__global__ __launch_bounds__(256) void wt_kernel(const float* __restrict__ in,
                                                 short* __restrict__ out,
                                                 int K, int N) {
    __shared__ float t[32][33];
    const int tid = threadIdx.x;
    const int c = tid & 31;
    const int r = tid >> 5;  // 0..7
    const int n0 = blockIdx.x * 32;
    const int k0 = blockIdx.y * 32;
#pragma unroll
    for (int i = 0; i < 4; i++)
        t[r + 8 * i][c] = in[(size_t)(k0 + r + 8 * i) * N + n0 + c];
    __syncthreads();
#pragma unroll
    for (int i = 0; i < 4; i++)
        out[(size_t)(n0 + r + 8 * i) * K + k0 + c] = f2bf(t[c][r + 8 * i]);
}

// ---------------------------------------------------------------------------
// bf16 MFMA GEMM (m97 structure): C[M,N] = A[M,K] @ BT[N,K]^T + bias
// 128x128 tile, BK=32, 256 threads (4 waves, 2x2), 16x16x32 MFMA, 4x4 frags.
// Linear LDS [128][32] bf16, staged via global_load_lds width-16.
// ---------------------------------------------------------------------------
template <int RELU, int BF16OUT>
__global__ __launch_bounds__(256) void gemm_bf16_kernel(
    const short* __restrict__ A,    // [M][K] bf16
    const short* __restrict__ BT,   // [N][K] bf16
    const float* __restrict__ bias, // [N] fp32
    float* __restrict__ Cf,
    short* __restrict__ Cb,
    int M, int N, int K) {
    __shared__ __align__(16) short As[128 * 32];
    __shared__ __align__(16) short Bs[128 * 32];

    const int tid = threadIdx.x;
    const int lane = tid & 63;
    const int w = tid >> 6;
    const int wm = w >> 1, wn = w & 1;
    const int r0 = blockIdx.y * 128;
    const int c0 = blockIdx.x * 128;

    f32x4 acc[4][4];
#pragma unroll
    for (int i = 0; i < 4; i++)
#pragma unroll
        for (int j = 0; j < 4; j++) acc[i][j] = f32x4{0.f, 0.f, 0.f, 0.f};

    // staging: chunk cj (0..7) covers tile rows cj*16..cj*16+15; within a
    // wave, lane covers row cj*16 + lane/4, k-slot (lane&3)*8 (16B each).
    const int srow = lane >> 2;
    const int skel = (lane & 3) * 8;
    const short* Ag0 = A + (size_t)(r0 + w * 16 + srow) * K + skel;
    const short* Ag1 = A + (size_t)(r0 + (4 + w) * 16 + srow) * K + skel;
    const short* Bg0 = BT + (size_t)(c0 + w * 16 + srow) * K + skel;
    const short* Bg1 = BT + (size_t)(c0 + (4 + w) * 16 + srow) * K + skel;

    char* AsB = (char*)As;
    char* BsB = (char*)Bs;

    for (int k0 = 0; k0 < K; k0 += 32) {
        __syncthreads();  // previous compute done before overwrite
        __builtin_amdgcn_global_load_lds(
            (const __attribute__((address_space(1))) void*)(Ag0 + k0),
            (__attribute__((address_space(3))) void*)(AsB + (size_t)w * 1024), 16, 0, 0);
        __builtin_amdgcn_global_load_lds(
            (const __attribute__((address_space(1))) void*)(Ag1 + k0),
            (__attribute__((address_space(3))) void*)(AsB + (size_t)(4 + w) * 1024), 16, 0, 0);
        __builtin_amdgcn_global_load_lds(
            (const __attribute__((address_space(1))) void*)(Bg0 + k0),
            (__attribute__((address_space(3))) void*)(BsB + (size_t)w * 1024), 16, 0, 0);
        __builtin_amdgcn_global_load_lds(
            (const __attribute__((address_space(1))) void*)(Bg1 + k0),
            (__attribute__((address_space(3))) void*)(BsB + (size_t)(4 + w) * 1024), 16, 0, 0);
        __syncthreads();  // drains vmcnt before barrier (compiler-inserted)

        short8 af[4], bfr[4];
#pragma unroll
        for (int i = 0; i < 4; i++) {
            af[i]  = *(const short8*)&As[(wm * 64 + i * 16 + (lane & 15)) * 32 + (lane >> 4) * 8];
            bfr[i] = *(const short8*)&Bs[(wn * 64 + i * 16 + (lane & 15)) * 32 + (lane >> 4) * 8];
        }
#pragma unroll
        for (int mi = 0; mi < 4; mi++)
#pragma unroll
            for (int ni = 0; ni < 4; ni++)
                acc[mi][ni] = __builtin_amdgcn_mfma_f32_16x16x32_bf16(
                    af[mi], bfr[ni], acc[mi][ni], 0, 0, 0);
    }

#pragma unroll
    for (int mi = 0; mi < 4; mi++) {
#pragma unroll
        for (int ni = 0; ni < 4; ni++) {
            const int col = c0 + wn * 64 + ni * 16 + (lane & 15);
            const float bv = bias[col];
#pragma unroll
            for (int i = 0; i < 4; i++) {
                const int row = r0 + wm * 64 + mi * 16 + (lane >> 4) * 4 + i;
                float v = acc[mi][ni][i] + bv;
                if (RELU) v = fmaxf(v, 0.f);
                if (BF16OUT) Cb[(size_t)row * N + col] = f2bf(v);
                else         Cf[(size_t)row * N + col] = v;
            }
        }
    }
}

// ---------------------------------------------------------------------------
// Causal attention, lane-parallel (lane = key index s within tile).
// Unchanged from R2 except ctx output is bf16.
// ---------------------------------------------------------------------------
__global__ __launch_bounds__(256) void attn_kernel(const float* __restrict__ qkv,
                                                   short* __restrict__ ctx) {
    __shared__ float4 ks4[16 * 64];
    __shared__ float4 vs4[16 * 64];

    const int tid = threadIdx.x;
    const int lane = tid & 63;
    const int w = tid >> 6;
    const int rb = blockIdx.x * 4;
    const int tbase = rb % TSEQ;
    const int t = tbase + w;
    const int bh = rb / TSEQ;
    const int b = bh / NHEADS;
    const int h = bh % NHEADS;

    const float4* qptr = (const float4*)(qkv + ((size_t)b * TSEQ + t) * (3 * DIMX) + h * DKH);
    float4 q4[16];
#pragma unroll
    for (int i = 0; i < 16; i++) q4[i] = qptr[i];

    float acc[64];
#pragma unroll
    for (int i = 0; i < 64; i++) acc[i] = 0.f;
    float m = -INFINITY, lsum = 0.f;

    int ridx[16];
#pragma unroll
    for (int c = 0; c < 16; c++) ridx[c] = lane * 16 + (c ^ (lane & 7));

    const int sc_ = tid & 15;
    const int sr_ = tid >> 4;
    const int smax = tbase + 3;

    for (int s0 = 0; s0 <= smax; s0 += 64) {
        const int scount = min(64, smax + 1 - s0);
        __syncthreads();
#pragma unroll
        for (int i = 0; i < 4; i++) {
            int s = sr_ + i * 16;
            int slot = s * 16 + (sc_ ^ (s & 7));
            if (s < scount) {
                const float* kp = qkv + ((size_t)b * TSEQ + s0 + s) * (3 * DIMX)
                                + DIMX + h * DKH + sc_ * 4;
                ks4[slot] = *(const float4*)kp;
                vs4[slot] = *(const float4*)(kp + DIMX);
            } else {
                ks4[slot] = float4{0.f, 0.f, 0.f, 0.f};
                vs4[slot] = float4{0.f, 0.f, 0.f, 0.f};
            }
        }
        __syncthreads();

        float sc = 0.f;
#pragma unroll
        for (int c = 0; c < 16; c++) {
            float4 kv = ks4[ridx[c]];
            sc += q4[c].x * kv.x + q4[c].y * kv.y + q4[c].z * kv.z + q4[c].w * kv.w;
        }
        sc *= 0.125f;
        sc = (s0 + lane <= t) ? sc : -1e30f;

        float tmax = sc;
#pragma unroll
        for (int off = 32; off; off >>= 1) tmax = fmaxf(tmax, __shfl_xor(tmax, off));

        if (tmax > m + 8.f) {
            float corr = __expf(m - tmax);
#pragma unroll
            for (int i = 0; i < 64; i++) acc[i] *= corr;
            lsum *= corr;
            m = tmax;
        }
        float p = __expf(sc - m);
        lsum += p;

#pragma unroll
        for (int c = 0; c < 16; c++) {
            float4 vv = vs4[ridx[c]];
            acc[c * 4 + 0] += p * vv.x;
            acc[c * 4 + 1] += p * vv.y;
            acc[c * 4 + 2] += p * vv.z;
            acc[c * 4 + 3] += p * vv.w;
        }
    }

#pragma unroll
    for (int off = 32; off; off >>= 1) lsum += __shfl_xor(lsum, off);

#define RSTEP(OFF)                                                         \
    {                                                                      \
        bool hi = (lane & OFF) != 0;                                       \
        _Pragma("unroll")                                                  \
        for (int i = 0; i < OFF; i++) {                                    \
            float keep = hi ? acc[i + OFF] : acc[i];                       \
            float send = hi ? acc[i] : acc[i + OFF];                       \
            acc[i] = keep + __shfl_xor(send, OFF);                         \
        }                                                                  \
    }
    RSTEP(32) RSTEP(16) RSTEP(8) RSTEP(4) RSTEP(2) RSTEP(1)
#undef RSTEP

    ctx[((size_t)b * TSEQ + t) * DIMX + h * DKH + lane] = f2bf(acc[0] / lsum);
}

// ---------------------------------------------------------------------------
// Fused residual + LayerNorm: out = LN(resid + y)*g + b  (fp32 + bf16 outputs)
// ---------------------------------------------------------------------------
__global__ __launch_bounds__(256) void ln_kernel(const float* __restrict__ resid,
                                                 const float* __restrict__ y,
                                                 const float* __restrict__ g,
                                                 const float* __restrict__ bta,
                                                 float* __restrict__ out,
                                                 short* __restrict__ outb) {
    const int row = blockIdx.x;
    const int tid = threadIdx.x;
    __shared__ float red[4];

    float v[3];
#pragma unroll
    for (int i = 0; i < 3; i++) {
        int idx = tid + i * 256;
        size_t p = (size_t)row * DIMX + idx;
        v[i] = resid[p] + y[p];
    }
    float part = v[0] + v[1] + v[2];
#pragma unroll
    for (int off = 32; off; off >>= 1) part += __shfl_xor(part, off, 64);
    if ((tid & 63) == 0) red[tid >> 6] = part;
    __syncthreads();
    const float mean = (red[0] + red[1] + red[2] + red[3]) * (1.f / 768.f);

    float p2 = 0.f;
#pragma unroll
    for (int i = 0; i < 3; i++) {
        float d = v[i] - mean;
        p2 += d * d;
    }
#pragma unroll
    for (int off = 32; off; off >>= 1) p2 += __shfl_xor(p2, off, 64);
    __syncthreads();
    if ((tid & 63) == 0) red[tid >> 6] = p2;
    __syncthreads();
    const float var = (red[0] + red[1] + red[2] + red[3]) * (1.f / 768.f);
    const float inv = rsqrtf(var + 1e-5f);

#pragma unroll
    for (int i = 0; i < 3; i++) {
        int idx = tid + i * 256;
        float r = (v[i] - mean) * inv * g[idx] + bta[idx];
        out[(size_t)row * DIMX + idx] = r;
        outb[(size_t)row * DIMX + idx] = f2bf(r);
    }
}

// ---------------------------------------------------------------------------
extern "C" void kernel_launch(void* const* d_in, const int* in_sizes, int n_in,
                              void* d_out, int out_size, void* d_ws, size_t ws_size,
                              hipStream_t stream) {
    (void)in_sizes; (void)n_in; (void)out_size; (void)ws_size;
    const float* x     = (const float*)d_in[0];
    const float* qkv_w = (const float*)d_in[2];
    const float* qkv_b = (const float*)d_in[3];
    const float* out_w = (const float*)d_in[4];
    const float* out_b = (const float*)d_in[5];
    const float* ff1_w = (const float*)d_in[6];
    const float* ff1_b = (const float*)d_in[7];
    const float* ff2_w = (const float*)d_in[8];
    const float* ff2_b = (const float*)d_in[9];
    const float* ln1_g = (const float*)d_in[10];
    const float* ln1_b = (const float*)d_in[11];
    const float* ln2_g = (const float*)d_in[12];
    const float* ln2_b = (const float*)d_in[13];

    // ws layout
    char* p = (char*)d_ws;
    float* h     = (float*)p;  p += (size_t)MROWS * DIMX * 4;       // fp32 [4096,768]
    float* qkv   = (float*)p;  p += (size_t)MROWS * 3 * DIMX * 4;   // fp32 [4096,2304]
    float* y     = (float*)p;  p += (size_t)MROWS * DIMX * 4;       // fp32 [4096,768]
    short* h_bf  = (short*)p;  p += (size_t)MROWS * DIMX * 2;       // bf16 [4096,768]
    short* ctx_bf= (short*)p;  p += (size_t)MROWS * DIMX * 2;       // bf16 [4096,768]
    short* ff_bf = (short*)p;  p += (size_t)MROWS * FFDIM * 2;      // bf16 [4096,3072]
    short* qkvT  = (short*)p;  p += (size_t)DEPTH * 3 * DIMX * DIMX * 2;  // [2304,768] x4
    short* outT  = (short*)p;  p += (size_t)DEPTH * DIMX * DIMX * 2;      // [768,768]  x4
    short* ff1T  = (short*)p;  p += (size_t)DEPTH * FFDIM * DIMX * 2;     // [3072,768] x4
    short* ff2T  = (short*)p;  p += (size_t)DEPTH * DIMX * FFDIM * 2;     // [768,3072] x4

    // weight transpose+convert (every call; ~30us total)
    for (int l = 0; l < DEPTH; ++l) {
        wt_kernel<<<dim3(3 * DIMX / 32, DIMX / 32), 256, 0, stream>>>(
            qkv_w + (size_t)l * DIMX * 3 * DIMX, qkvT + (size_t)l * 3 * DIMX * DIMX,
            DIMX, 3 * DIMX);
        wt_kernel<<<dim3(DIMX / 32, DIMX / 32), 256, 0, stream>>>(
            out_w + (size_t)l * DIMX * DIMX, outT + (size_t)l * DIMX * DIMX,
            DIMX, DIMX);
        wt_kernel<<<dim3(FFDIM / 32, DIMX / 32), 256, 0, stream>>>(
            ff1_w + (size_t)l * DIMX * FFDIM, ff1T + (size_t)l * FFDIM * DIMX,
            DIMX, FFDIM);
        wt_kernel<<<dim3(DIMX / 32, FFDIM / 32), 256, 0, stream>>>(
            ff2_w + (size_t)l * FFDIM * DIMX, ff2T + (size_t)l * DIMX * FFDIM,
            FFDIM, DIMX);
    }

    pe_add_kernel<<<(MROWS * DIMX + 255) / 256, 256, 0, stream>>>(x, h, h_bf);

    for (int l = 0; l < DEPTH; ++l) {
        gemm_bf16_kernel<0, 0><<<dim3(3 * DIMX / 128, MROWS / 128), 256, 0, stream>>>(
            h_bf, qkvT + (size_t)l * 3 * DIMX * DIMX, qkv_b + (size_t)l * 3 * DIMX,
            qkv, nullptr, MROWS, 3 * DIMX, DIMX);
        attn_kernel<<<BBATCH * NHEADS * TSEQ / 4, 256, 0, stream>>>(qkv, ctx_bf);
        gemm_bf16_kernel<0, 0><<<dim3(DIMX / 128, MROWS / 128), 256, 0, stream>>>(
            ctx_bf, outT + (size_t)l * DIMX * DIMX, out_b + (size_t)l * DIMX,
            y, nullptr, MROWS, DIMX, DIMX);
        ln_kernel<<<MROWS, 256, 0, stream>>>(h, y, ln1_g + (size_t)l * DIMX,
                                             ln1_b + (size_t)l * DIMX, h, h_bf);
        gemm_bf16_kernel<1, 1><<<dim3(FFDIM / 128, MROWS / 128), 256, 0, stream>>>(
            h_bf, ff1T + (size_t)l * FFDIM * DIMX, ff1_b + (size_t)l * FFDIM,
            nullptr, ff_bf, MROWS, FFDIM, DIMX);
        gemm_bf16_kernel<0, 0><<<dim3(DIMX / 128, MROWS / 128), 256, 0, stream>>>(
            ff_bf, ff2T + (size_t)l * DIMX * FFDIM, ff2_b + (size_t)l * DIMX,
            y, nullptr, MROWS, DIMX, FFDIM);
        ln_kernel<<<MROWS, 256, 0, stream>>>(h, y, ln2_g + (size_t)l * DIMX,
                                             ln2_b + (size_t)l * DIMX, h, h_bf);
    }
    hipMemcpyAsync(d_out, h, (size_t)MROWS * DIMX * sizeof(float),
                   hipMemcpyDeviceToDevice, stream);
}

// Round 5
// 1292.000 us; speedup vs baseline: 16.0445x; 3.3034x over previous
//
#include <hip/hip_runtime.h>
#include <hip/hip_bf16.h>
#include <math.h>

#define DIMX 768
#define DEPTH 4
#define NHEADS 12
#define FFDIM 3072
#define BBATCH 2
#define TSEQ 2048
#define DKH 64
#define MROWS (BBATCH * TSEQ)   // 4096
#define NBH (BBATCH * NHEADS)   // 24

typedef __attribute__((ext_vector_type(8))) short short8;
typedef __attribute__((ext_vector_type(4))) float f32x4;
typedef __attribute__((ext_vector_type(2))) unsigned uint2v;

__device__ __forceinline__ short f2bf(float f) {
    union { float f; unsigned u; } v; v.f = f;
    unsigned r = v.u + 0x7fff + ((v.u >> 16) & 1);   // RNE
    return (short)(r >> 16);
}
__device__ __forceinline__ unsigned pack2bf(float a, float b) {
    return ((unsigned)(unsigned short)f2bf(b) << 16) | (unsigned short)f2bf(a);
}

// ---------------------------------------------------------------------------
// Positional encoding add: h = x + PE  (fp32 + bf16 outputs)
// ---------------------------------------------------------------------------
__global__ __launch_bounds__(256) void pe_add_kernel(const float* __restrict__ x,
                                                     float* __restrict__ h,
                                                     short* __restrict__ hb) {
    int idx = blockIdx.x * 256 + threadIdx.x;
    int total = MROWS * DIMX;
    if (idx >= total) return;
    int d = idx % DIMX;
    int t = (idx / DIMX) % TSEQ;
    int i2 = d & ~1;
    float div = expf((float)i2 * (-9.210340371976184f / (float)DIMX));
    float ang = (float)t * div;
    float pe = (d & 1) ? cosf(ang) : sinf(ang);
    float r = x[idx] + pe;
    h[idx] = r;
    hb[idx] = f2bf(r);
}

// ---------------------------------------------------------------------------
// Weight transpose + fp32->bf16: in [K][N] fp32  ->  out [N][K] bf16
// ---------------------------------------------------------------------------
__global__ __launch_bounds__(256) void wt_kernel(const float* __restrict__ in,
                                                 short* __restrict__ out,
                                                 int K, int N) {
    __shared__ float t[32][33];
    const int tid = threadIdx.x;
    const int c = tid & 31;
    const int r = tid >> 5;  // 0..7
    const int n0 = blockIdx.x * 32;
    const int k0 = blockIdx.y * 32;
#pragma unroll
    for (int i = 0; i < 4; i++)
        t[r + 8 * i][c] = in[(size_t)(k0 + r + 8 * i) * N + n0 + c];
    __syncthreads();
#pragma unroll
    for (int i = 0; i < 4; i++)
        out[(size_t)(n0 + r + 8 * i) * K + k0 + c] = f2bf(t[c][r + 8 * i]);
}

// ---------------------------------------------------------------------------
// bf16 MFMA GEMM (m97 structure): C[M,N] = A[M,K] @ BT[N,K]^T + bias
// ---------------------------------------------------------------------------
template <int RELU, int BF16OUT>
__global__ __launch_bounds__(256) void gemm_bf16_kernel(
    const short* __restrict__ A,    // [M][K] bf16
    const short* __restrict__ BT,   // [N][K] bf16
    const float* __restrict__ bias, // [N] fp32
    float* __restrict__ Cf,
    short* __restrict__ Cb,
    int M, int N, int K) {
    __shared__ __align__(16) short As[128 * 32];
    __shared__ __align__(16) short Bs[128 * 32];

    const int tid = threadIdx.x;
    const int lane = tid & 63;
    const int w = tid >> 6;
    const int wm = w >> 1, wn = w & 1;
    const int r0 = blockIdx.y * 128;
    const int c0 = blockIdx.x * 128;

    f32x4 acc[4][4];
#pragma unroll
    for (int i = 0; i < 4; i++)
#pragma unroll
        for (int j = 0; j < 4; j++) acc[i][j] = f32x4{0.f, 0.f, 0.f, 0.f};

    const int srow = lane >> 2;
    const int skel = (lane & 3) * 8;
    const short* Ag0 = A + (size_t)(r0 + w * 16 + srow) * K + skel;
    const short* Ag1 = A + (size_t)(r0 + (4 + w) * 16 + srow) * K + skel;
    const short* Bg0 = BT + (size_t)(c0 + w * 16 + srow) * K + skel;
    const short* Bg1 = BT + (size_t)(c0 + (4 + w) * 16 + srow) * K + skel;

    char* AsB = (char*)As;
    char* BsB = (char*)Bs;

    for (int k0 = 0; k0 < K; k0 += 32) {
        __syncthreads();
        __builtin_amdgcn_global_load_lds(
            (const __attribute__((address_space(1))) void*)(Ag0 + k0),
            (__attribute__((address_space(3))) void*)(AsB + (size_t)w * 1024), 16, 0, 0);
        __builtin_amdgcn_global_load_lds(
            (const __attribute__((address_space(1))) void*)(Ag1 + k0),
            (__attribute__((address_space(3))) void*)(AsB + (size_t)(4 + w) * 1024), 16, 0, 0);
        __builtin_amdgcn_global_load_lds(
            (const __attribute__((address_space(1))) void*)(Bg0 + k0),
            (__attribute__((address_space(3))) void*)(BsB + (size_t)w * 1024), 16, 0, 0);
        __builtin_amdgcn_global_load_lds(
            (const __attribute__((address_space(1))) void*)(Bg1 + k0),
            (__attribute__((address_space(3))) void*)(BsB + (size_t)(4 + w) * 1024), 16, 0, 0);
        __syncthreads();

        short8 af[4], bfr[4];
#pragma unroll
        for (int i = 0; i < 4; i++) {
            af[i]  = *(const short8*)&As[(wm * 64 + i * 16 + (lane & 15)) * 32 + (lane >> 4) * 8];
            bfr[i] = *(const short8*)&Bs[(wn * 64 + i * 16 + (lane & 15)) * 32 + (lane >> 4) * 8];
        }
#pragma unroll
        for (int mi = 0; mi < 4; mi++)
#pragma unroll
            for (int ni = 0; ni < 4; ni++)
                acc[mi][ni] = __builtin_amdgcn_mfma_f32_16x16x32_bf16(
                    af[mi], bfr[ni], acc[mi][ni], 0, 0, 0);
    }

#pragma unroll
    for (int mi = 0; mi < 4; mi++) {
#pragma unroll
        for (int ni = 0; ni < 4; ni++) {
            const int col = c0 + wn * 64 + ni * 16 + (lane & 15);
            const float bv = bias[col];
#pragma unroll
            for (int i = 0; i < 4; i++) {
                const int row = r0 + wm * 64 + mi * 16 + (lane >> 4) * 4 + i;
                float v = acc[mi][ni][i] + bv;
                if (RELU) v = fmaxf(v, 0.f);
                if (BF16OUT) Cb[(size_t)row * N + col] = f2bf(v);
                else         Cf[(size_t)row * N + col] = v;
            }
        }
    }
}

// ---------------------------------------------------------------------------
// V transpose: qkv_bf V block [B,T,H,64] -> vt [bh][64 d][T s]  (bf16)
// ---------------------------------------------------------------------------
__global__ __launch_bounds__(256) void vt_kernel(const short* __restrict__ qkvb,
                                                 short* __restrict__ vt) {
    __shared__ short tile[64][72];
    const int tid = threadIdx.x;
    const int bh = blockIdx.x % NBH;
    const int s0 = (blockIdx.x / NBH) * 64;
    const int b = bh / NHEADS, h = bh % NHEADS;
    const int r = tid >> 3, c8 = (tid & 7) * 8;
#pragma unroll
    for (int i = 0; i < 2; ++i) {
        const int s = r + 32 * i;
        short8 v = *(const short8*)(qkvb + ((size_t)b * TSEQ + s0 + s) * (3 * DIMX)
                                    + 2 * DIMX + h * DKH + c8);
#pragma unroll
        for (int e = 0; e < 8; ++e) tile[c8 + e][s] = v[e];
    }
    __syncthreads();
#pragma unroll
    for (int i = 0; i < 2; ++i) {
        const int d = r + 32 * i;
        short8 o = *(const short8*)&tile[d][c8];
        *(short8*)(vt + ((size_t)bh * DKH + d) * TSEQ + s0 + c8) = o;
    }
}

// ---------------------------------------------------------------------------
// MFMA flash attention. Block = 128 q rows (4 waves x 32 q, interleaved
// 16-row blocks), K-tile = 64 keys. Swapped QK^T (mfma(K,Q)) so softmax is
// 2 shfl_xor; P repacked to bf16 in-register, shuffled into PV B-fragments;
// PV = mfma(V^T, P^T) accumulating O^T. K/V^T staged with global_load_lds,
// XOR-swizzled source (16B slots, key row&7).
// ---------------------------------------------------------------------------
__device__ __forceinline__ void attn_process_qb(
    f32x4* SF, f32x4* OF, float& m, float& l,
    const short* Vs, int s0, int trow, bool maskq, int g, int q) {
    float mx = -3.0e38f;
#pragma unroll
    for (int f = 0; f < 4; ++f) {
#pragma unroll
        for (int i = 0; i < 4; ++i) {
            float v = SF[f][i] * 0.125f;   // 1/sqrt(64)
            if (maskq && (s0 + 16 * f + 4 * g + i > trow)) v = -1e30f;
            SF[f][i] = v;
            mx = fmaxf(mx, v);
        }
    }
    mx = fmaxf(mx, __shfl_xor(mx, 16));
    mx = fmaxf(mx, __shfl_xor(mx, 32));
    const float mnew = fmaxf(m, mx);
    const float corr = __expf(m - mnew);
    float ts = 0.f;
    unsigned pk01[4], pk23[4];
#pragma unroll
    for (int f = 0; f < 4; ++f) {
#pragma unroll
        for (int i = 0; i < 4; ++i) {
            float p = __expf(SF[f][i] - mnew);
            SF[f][i] = p;
            ts += p;
        }
        pk01[f] = pack2bf(SF[f][0], SF[f][1]);
        pk23[f] = pack2bf(SF[f][2], SF[f][3]);
    }
    ts += __shfl_xor(ts, 16);
    ts += __shfl_xor(ts, 32);
    l = l * corr + ts;
    m = mnew;
#pragma unroll
    for (int d = 0; d < 4; ++d) OF[d] *= corr;

    // PV: B-frag for k-block kb needs P[q][s = 32kb + 8g + j], j=0..7:
    // lo j=0..3 from lane (g&1)*32+q, hi from +16, frag f' = 2kb + (g>>1).
    const int lsrc = ((g & 1) << 5) + q;
    const bool fhi = (g >> 1) != 0;
#pragma unroll
    for (int kb = 0; kb < 2; ++kb) {
        unsigned w0a = __shfl((int)pk01[2 * kb],     lsrc);
        unsigned w1a = __shfl((int)pk23[2 * kb],     lsrc);
        unsigned w0b = __shfl((int)pk01[2 * kb + 1], lsrc);
        unsigned w1b = __shfl((int)pk23[2 * kb + 1], lsrc);
        unsigned w2a = __shfl((int)pk01[2 * kb],     lsrc + 16);
        unsigned w3a = __shfl((int)pk23[2 * kb],     lsrc + 16);
        unsigned w2b = __shfl((int)pk01[2 * kb + 1], lsrc + 16);
        unsigned w3b = __shfl((int)pk23[2 * kb + 1], lsrc + 16);
        union { unsigned u[4]; short8 v; } bb;
        bb.u[0] = fhi ? w0b : w0a;
        bb.u[1] = fhi ? w1b : w1a;
        bb.u[2] = fhi ? w2b : w2a;
        bb.u[3] = fhi ? w3b : w3a;
#pragma unroll
        for (int db = 0; db < 4; ++db) {
            const int row = 16 * db + q;
            short8 vf = *(const short8*)&Vs[row * 64 + ((((kb << 2) + g)) ^ (q & 7)) * 8];
            OF[db] = __builtin_amdgcn_mfma_f32_16x16x32_bf16(vf, bb.v, OF[db], 0, 0, 0);
        }
    }
}

__global__ __launch_bounds__(256) void attn_mfma_kernel(
    const short* __restrict__ qkvb, const short* __restrict__ vt,
    short* __restrict__ ctx) {
    __shared__ __align__(16) short Ks[64 * 64];   // [s][d], slot-swizzled
    __shared__ __align__(16) short Vs[64 * 64];   // [d][s], slot-swizzled

    const int tid = threadIdx.x;
    const int lane = tid & 63;
    const int w = tid >> 6;
    const int g = lane >> 4;
    const int q = lane & 15;

    const int bh = blockIdx.x % NBH;
    const int j  = 15 - blockIdx.x / NBH;     // heavy blocks first
    const int b = bh / NHEADS, h = bh % NHEADS;
    const int q0 = j * 128;
    const int base0 = q0 + w * 16;
    const int base1 = q0 + 64 + w * 16;
    const int trow0 = base0 + q;
    const int trow1 = base1 + q;

    short8 QF[2][2];
    {
        const short* qp0 = qkvb + ((size_t)b * TSEQ + trow0) * (3 * DIMX) + h * DKH;
        const short* qp1 = qkvb + ((size_t)b * TSEQ + trow1) * (3 * DIMX) + h * DKH;
        QF[0][0] = *(const short8*)(qp0 + g * 8);
        QF[0][1] = *(const short8*)(qp0 + 32 + g * 8);
        QF[1][0] = *(const short8*)(qp1 + g * 8);
        QF[1][1] = *(const short8*)(qp1 + 32 + g * 8);
    }

    f32x4 OF0[4], OF1[4];
#pragma unroll
    for (int d = 0; d < 4; ++d) {
        OF0[d] = f32x4{0.f, 0.f, 0.f, 0.f};
        OF1[d] = f32x4{0.f, 0.f, 0.f, 0.f};
    }
    float m0 = -INFINITY, l0 = 0.f, m1 = -INFINITY, l1 = 0.f;

    const int srow = lane >> 3;          // 0..7
    const int slot = lane & 7;
    const int sw8 = ((slot ^ srow)) * 8; // pre-swizzled 16B slot

    const short* kcol = qkvb + (size_t)b * TSEQ * (3 * DIMX) + DIMX + h * DKH;
    const short* vrow = vt + (size_t)bh * DKH * TSEQ;

    const int ntiles = 2 * j + 2;
    for (int tix = 0; tix < ntiles; ++tix) {
        const int s0 = tix * 64;
        const bool do0 = (tix != ntiles - 1);
        __syncthreads();
#pragma unroll
        for (int iss = 0; iss < 2; ++iss) {
            const int rb = 8 * w + 32 * iss;
            const short* ksrc = kcol + (size_t)(s0 + rb + srow) * (3 * DIMX) + sw8;
            const short* vsrc = vrow + (size_t)(rb + srow) * TSEQ + s0 + sw8;
            __builtin_amdgcn_global_load_lds(
                (const __attribute__((address_space(1))) void*)ksrc,
                (__attribute__((address_space(3))) void*)((char*)Ks + rb * 128), 16, 0, 0);
            __builtin_amdgcn_global_load_lds(
                (const __attribute__((address_space(1))) void*)vsrc,
                (__attribute__((address_space(3))) void*)((char*)Vs + rb * 128), 16, 0, 0);
        }
        __syncthreads();

        // swapped QK^T: SF[f] covers s-block [16f,16f+16), lane: s=16f+4g+i, col q
        f32x4 SF0[4], SF1[4];
#pragma unroll
        for (int f = 0; f < 4; ++f) {
            SF0[f] = f32x4{0.f, 0.f, 0.f, 0.f};
            SF1[f] = f32x4{0.f, 0.f, 0.f, 0.f};
        }
#pragma unroll
        for (int f = 0; f < 4; ++f) {
            const int rx = (16 * f + q) * 64;
            const int r7 = q & 7;
#pragma unroll
            for (int kd = 0; kd < 2; ++kd) {
                short8 kf = *(const short8*)&Ks[rx + (((kd << 2) + g) ^ r7) * 8];
                if (do0)
                    SF0[f] = __builtin_amdgcn_mfma_f32_16x16x32_bf16(kf, QF[0][kd], SF0[f], 0, 0, 0);
                SF1[f] = __builtin_amdgcn_mfma_f32_16x16x32_bf16(kf, QF[1][kd], SF1[f], 0, 0, 0);
            }
        }

        if (do0) {
            const bool mq0 = (s0 + 63 > base0);
            attn_process_qb(SF0, OF0, m0, l0, Vs, s0, trow0, mq0, g, q);
        }
        const bool mq1 = (s0 + 63 > base1);
        attn_process_qb(SF1, OF1, m1, l1, Vs, s0, trow1, mq1, g, q);
    }

    // epilogue: O^T[d][q] / l  ->  ctx[b*T + trow][h*64 + d]
    const float inv0 = 1.f / l0;
    const float inv1 = 1.f / l1;
#pragma unroll
    for (int db = 0; db < 4; ++db) {
        uint2v o0, o1;
        o0.x = pack2bf(OF0[db][0] * inv0, OF0[db][1] * inv0);
        o0.y = pack2bf(OF0[db][2] * inv0, OF0[db][3] * inv0);
        o1.x = pack2bf(OF1[db][0] * inv1, OF1[db][1] * inv1);
        o1.y = pack2bf(OF1[db][2] * inv1, OF1[db][3] * inv1);
        *(uint2v*)(ctx + ((size_t)b * TSEQ + trow0) * DIMX + h * DKH + db * 16 + g * 4) = o0;
        *(uint2v*)(ctx + ((size_t)b * TSEQ + trow1) * DIMX + h * DKH + db * 16 + g * 4) = o1;
    }
}

// ---------------------------------------------------------------------------
// Fused residual + LayerNorm: out = LN(resid + y)*g + b  (fp32 + bf16 outputs)
// ---------------------------------------------------------------------------
__global__ __launch_bounds__(256) void ln_kernel(const float* __restrict__ resid,
                                                 const float* __restrict__ y,
                                                 const float* __restrict__ g,
                                                 const float* __restrict__ bta,
                                                 float* __restrict__ out,
                                                 short* __restrict__ outb) {
    const int row = blockIdx.x;
    const int tid = threadIdx.x;
    __shared__ float red[4];

    float v[3];
#pragma unroll
    for (int i = 0; i < 3; i++) {
        int idx = tid + i * 256;
        size_t p = (size_t)row * DIMX + idx;
        v[i] = resid[p] + y[p];
    }
    float part = v[0] + v[1] + v[2];
#pragma unroll
    for (int off = 32; off; off >>= 1) part += __shfl_xor(part, off, 64);
    if ((tid & 63) == 0) red[tid >> 6] = part;
    __syncthreads();
    const float mean = (red[0] + red[1] + red[2] + red[3]) * (1.f / 768.f);

    float p2 = 0.f;
#pragma unroll
    for (int i = 0; i < 3; i++) {
        float d = v[i] - mean;
        p2 += d * d;
    }
#pragma unroll
    for (int off = 32; off; off >>= 1) p2 += __shfl_xor(p2, off, 64);
    __syncthreads();
    if ((tid & 63) == 0) red[tid >> 6] = p2;
    __syncthreads();
    const float var = (red[0] + red[1] + red[2] + red[3]) * (1.f / 768.f);
    const float inv = rsqrtf(var + 1e-5f);

#pragma unroll
    for (int i = 0; i < 3; i++) {
        int idx = tid + i * 256;
        float r = (v[i] - mean) * inv * g[idx] + bta[idx];
        out[(size_t)row * DIMX + idx] = r;
        outb[(size_t)row * DIMX + idx] = f2bf(r);
    }
}

// ---------------------------------------------------------------------------
extern "C" void kernel_launch(void* const* d_in, const int* in_sizes, int n_in,
                              void* d_out, int out_size, void* d_ws, size_t ws_size,
                              hipStream_t stream) {
    (void)in_sizes; (void)n_in; (void)out_size; (void)ws_size;
    const float* x     = (const float*)d_in[0];
    const float* qkv_w = (const float*)d_in[2];
    const float* qkv_b = (const float*)d_in[3];
    const float* out_w = (const float*)d_in[4];
    const float* out_b = (const float*)d_in[5];
    const float* ff1_w = (const float*)d_in[6];
    const float* ff1_b = (const float*)d_in[7];
    const float* ff2_w = (const float*)d_in[8];
    const float* ff2_b = (const float*)d_in[9];
    const float* ln1_g = (const float*)d_in[10];
    const float* ln1_b = (const float*)d_in[11];
    const float* ln2_g = (const float*)d_in[12];
    const float* ln2_b = (const float*)d_in[13];

    // ws layout
    char* p = (char*)d_ws;
    float* h      = (float*)p;  p += (size_t)MROWS * DIMX * 4;
    float* y      = (float*)p;  p += (size_t)MROWS * DIMX * 4;
    short* h_bf   = (short*)p;  p += (size_t)MROWS * DIMX * 2;
    short* ctx_bf = (short*)p;  p += (size_t)MROWS * DIMX * 2;
    short* ff_bf  = (short*)p;  p += (size_t)MROWS * FFDIM * 2;
    short* qkv_bf = (short*)p;  p += (size_t)MROWS * 3 * DIMX * 2;
    short* vtb    = (short*)p;  p += (size_t)NBH * DKH * TSEQ * 2;
    short* qkvT   = (short*)p;  p += (size_t)DEPTH * 3 * DIMX * DIMX * 2;
    short* outT   = (short*)p;  p += (size_t)DEPTH * DIMX * DIMX * 2;
    short* ff1T   = (short*)p;  p += (size_t)DEPTH * FFDIM * DIMX * 2;
    short* ff2T   = (short*)p;  p += (size_t)DEPTH * DIMX * FFDIM * 2;

    for (int l = 0; l < DEPTH; ++l) {
        wt_kernel<<<dim3(3 * DIMX / 32, DIMX / 32), 256, 0, stream>>>(
            qkv_w + (size_t)l * DIMX * 3 * DIMX, qkvT + (size_t)l * 3 * DIMX * DIMX,
            DIMX, 3 * DIMX);
        wt_kernel<<<dim3(DIMX / 32, DIMX / 32), 256, 0, stream>>>(
            out_w + (size_t)l * DIMX * DIMX, outT + (size_t)l * DIMX * DIMX,
            DIMX, DIMX);
        wt_kernel<<<dim3(FFDIM / 32, DIMX / 32), 256, 0, stream>>>(
            ff1_w + (size_t)l * DIMX * FFDIM, ff1T + (size_t)l * FFDIM * DIMX,
            DIMX, FFDIM);
        wt_kernel<<<dim3(DIMX / 32, FFDIM / 32), 256, 0, stream>>>(
            ff2_w + (size_t)l * FFDIM * DIMX, ff2T + (size_t)l * DIMX * FFDIM,
            FFDIM, DIMX);
    }

    pe_add_kernel<<<(MROWS * DIMX + 255) / 256, 256, 0, stream>>>(x, h, h_bf);

    for (int l = 0; l < DEPTH; ++l) {
        gemm_bf16_kernel<0, 1><<<dim3(3 * DIMX / 128, MROWS / 128), 256, 0, stream>>>(
            h_bf, qkvT + (size_t)l * 3 * DIMX * DIMX, qkv_b + (size_t)l * 3 * DIMX,
            nullptr, qkv_bf, MROWS, 3 * DIMX, DIMX);
        vt_kernel<<<NBH * (TSEQ / 64), 256, 0, stream>>>(qkv_bf, vtb);
        attn_mfma_kernel<<<NBH * 16, 256, 0, stream>>>(qkv_bf, vtb, ctx_bf);
        gemm_bf16_kernel<0, 0><<<dim3(DIMX / 128, MROWS / 128), 256, 0, stream>>>(
            ctx_bf, outT + (size_t)l * DIMX * DIMX, out_b + (size_t)l * DIMX,
            y, nullptr, MROWS, DIMX, DIMX);
        ln_kernel<<<MROWS, 256, 0, stream>>>(h, y, ln1_g + (size_t)l * DIMX,
                                             ln1_b + (size_t)l * DIMX, h, h_bf);
        gemm_bf16_kernel<1, 1><<<dim3(FFDIM / 128, MROWS / 128), 256, 0, stream>>>(
            h_bf, ff1T + (size_t)l * FFDIM * DIMX, ff1_b + (size_t)l * FFDIM,
            nullptr, ff_bf, MROWS, FFDIM, DIMX);
        gemm_bf16_kernel<0, 0><<<dim3(DIMX / 128, MROWS / 128), 256, 0, stream>>>(
            ff_bf, ff2T + (size_t)l * DIMX * FFDIM, ff2_b + (size_t)l * DIMX,
            y, nullptr, MROWS, DIMX, FFDIM);
        ln_kernel<<<MROWS, 256, 0, stream>>>(h, y, ln2_g + (size_t)l * DIMX,
                                             ln2_b + (size_t)l * DIMX, h, h_bf);
    }
    hipMemcpyAsync(d_out, h, (size_t)MROWS * DIMX * sizeof(float),
                   hipMemcpyDeviceToDevice, stream);
}

// Round 6
// 1118.155 us; speedup vs baseline: 18.5390x; 1.1555x over previous
//
#include <hip/hip_runtime.h>
#include <hip/hip_bf16.h>
#include <math.h>

#define DIMX 768
#define DEPTH 4
#define NHEADS 12
#define FFDIM 3072
#define BBATCH 2
#define TSEQ 2048
#define DKH 64
#define MROWS (BBATCH * TSEQ)   // 4096
#define NBH (BBATCH * NHEADS)   // 24

typedef __attribute__((ext_vector_type(8))) short short8;
typedef __attribute__((ext_vector_type(4))) float f32x4;
typedef __attribute__((ext_vector_type(2))) unsigned uint2v;

__device__ __forceinline__ short f2bf(float f) {
    union { float f; unsigned u; } v; v.f = f;
    unsigned r = v.u + 0x7fff + ((v.u >> 16) & 1);   // RNE
    return (short)(r >> 16);
}
__device__ __forceinline__ unsigned pack2bf(float a, float b) {
    return ((unsigned)(unsigned short)f2bf(b) << 16) | (unsigned short)f2bf(a);
}

// ---------------------------------------------------------------------------
// Positional encoding add: h = x + PE  (fp32 + bf16 outputs)
// ---------------------------------------------------------------------------
__global__ __launch_bounds__(256) void pe_add_kernel(const float* __restrict__ x,
                                                     float* __restrict__ h,
                                                     short* __restrict__ hb) {
    int idx = blockIdx.x * 256 + threadIdx.x;
    int total = MROWS * DIMX;
    if (idx >= total) return;
    int d = idx % DIMX;
    int t = (idx / DIMX) % TSEQ;
    int i2 = d & ~1;
    float div = expf((float)i2 * (-9.210340371976184f / (float)DIMX));
    float ang = (float)t * div;
    float pe = (d & 1) ? cosf(ang) : sinf(ang);
    float r = x[idx] + pe;
    h[idx] = r;
    hb[idx] = f2bf(r);
}

// ---------------------------------------------------------------------------
// Weight transpose + fp32->bf16: in [K][N] fp32  ->  out [N][K] bf16
// ---------------------------------------------------------------------------
__global__ __launch_bounds__(256) void wt_kernel(const float* __restrict__ in,
                                                 short* __restrict__ out,
                                                 int K, int N) {
    __shared__ float t[32][33];
    const int tid = threadIdx.x;
    const int c = tid & 31;
    const int r = tid >> 5;  // 0..7
    const int n0 = blockIdx.x * 32;
    const int k0 = blockIdx.y * 32;
#pragma unroll
    for (int i = 0; i < 4; i++)
        t[r + 8 * i][c] = in[(size_t)(k0 + r + 8 * i) * N + n0 + c];
    __syncthreads();
#pragma unroll
    for (int i = 0; i < 4; i++)
        out[(size_t)(n0 + r + 8 * i) * K + k0 + c] = f2bf(t[c][r + 8 * i]);
}

// ---------------------------------------------------------------------------
// bf16 MFMA GEMM (m97 structure): C[M,N] = A[M,K] @ BT[N,K]^T + bias
// ---------------------------------------------------------------------------
template <int RELU, int BF16OUT>
__global__ __launch_bounds__(256) void gemm_bf16_kernel(
    const short* __restrict__ A,    // [M][K] bf16
    const short* __restrict__ BT,   // [N][K] bf16
    const float* __restrict__ bias, // [N] fp32
    float* __restrict__ Cf,
    short* __restrict__ Cb,
    int M, int N, int K) {
    __shared__ __align__(16) short As[128 * 32];
    __shared__ __align__(16) short Bs[128 * 32];

    const int tid = threadIdx.x;
    const int lane = tid & 63;
    const int w = tid >> 6;
    const int wm = w >> 1, wn = w & 1;
    const int r0 = blockIdx.y * 128;
    const int c0 = blockIdx.x * 128;

    f32x4 acc[4][4];
#pragma unroll
    for (int i = 0; i < 4; i++)
#pragma unroll
        for (int j = 0; j < 4; j++) acc[i][j] = f32x4{0.f, 0.f, 0.f, 0.f};

    const int srow = lane >> 2;
    const int skel = (lane & 3) * 8;
    const short* Ag0 = A + (size_t)(r0 + w * 16 + srow) * K + skel;
    const short* Ag1 = A + (size_t)(r0 + (4 + w) * 16 + srow) * K + skel;
    const short* Bg0 = BT + (size_t)(c0 + w * 16 + srow) * K + skel;
    const short* Bg1 = BT + (size_t)(c0 + (4 + w) * 16 + srow) * K + skel;

    char* AsB = (char*)As;
    char* BsB = (char*)Bs;

    for (int k0 = 0; k0 < K; k0 += 32) {
        __syncthreads();
        __builtin_amdgcn_global_load_lds(
            (const __attribute__((address_space(1))) void*)(Ag0 + k0),
            (__attribute__((address_space(3))) void*)(AsB + (size_t)w * 1024), 16, 0, 0);
        __builtin_amdgcn_global_load_lds(
            (const __attribute__((address_space(1))) void*)(Ag1 + k0),
            (__attribute__((address_space(3))) void*)(AsB + (size_t)(4 + w) * 1024), 16, 0, 0);
        __builtin_amdgcn_global_load_lds(
            (const __attribute__((address_space(1))) void*)(Bg0 + k0),
            (__attribute__((address_space(3))) void*)(BsB + (size_t)w * 1024), 16, 0, 0);
        __builtin_amdgcn_global_load_lds(
            (const __attribute__((address_space(1))) void*)(Bg1 + k0),
            (__attribute__((address_space(3))) void*)(BsB + (size_t)(4 + w) * 1024), 16, 0, 0);
        __syncthreads();

        short8 af[4], bfr[4];
#pragma unroll
        for (int i = 0; i < 4; i++) {
            af[i]  = *(const short8*)&As[(wm * 64 + i * 16 + (lane & 15)) * 32 + (lane >> 4) * 8];
            bfr[i] = *(const short8*)&Bs[(wn * 64 + i * 16 + (lane & 15)) * 32 + (lane >> 4) * 8];
        }
#pragma unroll
        for (int mi = 0; mi < 4; mi++)
#pragma unroll
            for (int ni = 0; ni < 4; ni++)
                acc[mi][ni] = __builtin_amdgcn_mfma_f32_16x16x32_bf16(
                    af[mi], bfr[ni], acc[mi][ni], 0, 0, 0);
    }

#pragma unroll
    for (int mi = 0; mi < 4; mi++) {
#pragma unroll
        for (int ni = 0; ni < 4; ni++) {
            const int col = c0 + wn * 64 + ni * 16 + (lane & 15);
            const float bv = bias[col];
#pragma unroll
            for (int i = 0; i < 4; i++) {
                const int row = r0 + wm * 64 + mi * 16 + (lane >> 4) * 4 + i;
                float v = acc[mi][ni][i] + bv;
                if (RELU) v = fmaxf(v, 0.f);
                if (BF16OUT) Cb[(size_t)row * N + col] = f2bf(v);
                else         Cf[(size_t)row * N + col] = v;
            }
        }
    }
}

// ---------------------------------------------------------------------------
// V transpose: qkv_bf V block [B,T,H,64] -> vt [bh][64 d][T s]  (bf16)
// ---------------------------------------------------------------------------
__global__ __launch_bounds__(256) void vt_kernel(const short* __restrict__ qkvb,
                                                 short* __restrict__ vt) {
    __shared__ short tile[64][72];
    const int tid = threadIdx.x;
    const int bh = blockIdx.x % NBH;
    const int s0 = (blockIdx.x / NBH) * 64;
    const int b = bh / NHEADS, h = bh % NHEADS;
    const int r = tid >> 3, c8 = (tid & 7) * 8;
#pragma unroll
    for (int i = 0; i < 2; ++i) {
        const int s = r + 32 * i;
        short8 v = *(const short8*)(qkvb + ((size_t)b * TSEQ + s0 + s) * (3 * DIMX)
                                    + 2 * DIMX + h * DKH + c8);
#pragma unroll
        for (int e = 0; e < 8; ++e) tile[c8 + e][s] = v[e];
    }
    __syncthreads();
#pragma unroll
    for (int i = 0; i < 2; ++i) {
        const int d = r + 32 * i;
        short8 o = *(const short8*)&tile[d][c8];
        *(short8*)(vt + ((size_t)bh * DKH + d) * TSEQ + s0 + c8) = o;
    }
}

// ---------------------------------------------------------------------------
// MFMA flash attention, v2: 64 q-rows/block (4 waves x 16 q), double-buffered
// K/V LDS with 2-phase prefetch (stage next tile before computing current,
// raw vmcnt(0)+s_barrier per tile), setprio around MFMA, defer-rescale THR=8.
// ---------------------------------------------------------------------------
__device__ __forceinline__ void attn_process_qb(
    f32x4* SF, f32x4* OF, float& m, float& l,
    const short* Vs, int s0, int trow, bool maskq, int g, int q) {
    float mx = -3.0e38f;
#pragma unroll
    for (int f = 0; f < 4; ++f) {
#pragma unroll
        for (int i = 0; i < 4; ++i) {
            float v = SF[f][i] * 0.125f;   // 1/sqrt(64)
            if (maskq && (s0 + 16 * f + 4 * g + i > trow)) v = -1e30f;
            SF[f][i] = v;
            mx = fmaxf(mx, v);
        }
    }
    mx = fmaxf(mx, __shfl_xor(mx, 16));
    mx = fmaxf(mx, __shfl_xor(mx, 32));
    if (mx > m + 8.f) {                  // defer-rescale (T13, THR=8)
        const float corr = __expf(m - mx);
#pragma unroll
        for (int d = 0; d < 4; ++d) OF[d] *= corr;
        l *= corr;
        m = mx;
    }
    float ts = 0.f;
    unsigned pk01[4], pk23[4];
#pragma unroll
    for (int f = 0; f < 4; ++f) {
#pragma unroll
        for (int i = 0; i < 4; ++i) {
            float p = __expf(SF[f][i] - m);
            SF[f][i] = p;
            ts += p;
        }
        pk01[f] = pack2bf(SF[f][0], SF[f][1]);
        pk23[f] = pack2bf(SF[f][2], SF[f][3]);
    }
    ts += __shfl_xor(ts, 16);
    ts += __shfl_xor(ts, 32);
    l += ts;

    // PV: B-frag for k-block kb needs P[q][s = 32kb + 8g + j], j=0..7:
    // lo j=0..3 from lane (g&1)*32+q, hi from +16, frag f' = 2kb + (g>>1).
    const int lsrc = ((g & 1) << 5) + q;
    const bool fhi = (g >> 1) != 0;
    __builtin_amdgcn_s_setprio(1);
#pragma unroll
    for (int kb = 0; kb < 2; ++kb) {
        unsigned w0a = __shfl((int)pk01[2 * kb],     lsrc);
        unsigned w1a = __shfl((int)pk23[2 * kb],     lsrc);
        unsigned w0b = __shfl((int)pk01[2 * kb + 1], lsrc);
        unsigned w1b = __shfl((int)pk23[2 * kb + 1], lsrc);
        unsigned w2a = __shfl((int)pk01[2 * kb],     lsrc + 16);
        unsigned w3a = __shfl((int)pk23[2 * kb],     lsrc + 16);
        unsigned w2b = __shfl((int)pk01[2 * kb + 1], lsrc + 16);
        unsigned w3b = __shfl((int)pk23[2 * kb + 1], lsrc + 16);
        union { unsigned u[4]; short8 v; } bb;
        bb.u[0] = fhi ? w0b : w0a;
        bb.u[1] = fhi ? w1b : w1a;
        bb.u[2] = fhi ? w2b : w2a;
        bb.u[3] = fhi ? w3b : w3a;
#pragma unroll
        for (int db = 0; db < 4; ++db) {
            const int row = 16 * db + q;
            short8 vf = *(const short8*)&Vs[row * 64 + ((((kb << 2) + g)) ^ (q & 7)) * 8];
            OF[db] = __builtin_amdgcn_mfma_f32_16x16x32_bf16(vf, bb.v, OF[db], 0, 0, 0);
        }
    }
    __builtin_amdgcn_s_setprio(0);
}

__global__ __launch_bounds__(256) void attn_mfma_kernel(
    const short* __restrict__ qkvb, const short* __restrict__ vt,
    short* __restrict__ ctx) {
    __shared__ __align__(16) short Ks[2][64 * 64];   // [s][d], slot-swizzled
    __shared__ __align__(16) short Vs[2][64 * 64];   // [d][s], slot-swizzled

    const int tid = threadIdx.x;
    const int lane = tid & 63;
    const int w = tid >> 6;
    const int g = lane >> 4;
    const int q = lane & 15;

    const int bh = blockIdx.x % NBH;
    const int j  = 31 - blockIdx.x / NBH;     // heavy blocks first
    const int b = bh / NHEADS, h = bh % NHEADS;
    const int q0 = j * 64;
    const int base = q0 + w * 16;
    const int trow = base + q;

    short8 QF[2];
    {
        const short* qp = qkvb + ((size_t)b * TSEQ + trow) * (3 * DIMX) + h * DKH;
        QF[0] = *(const short8*)(qp + g * 8);
        QF[1] = *(const short8*)(qp + 32 + g * 8);
    }

    f32x4 OF[4];
#pragma unroll
    for (int d = 0; d < 4; ++d) OF[d] = f32x4{0.f, 0.f, 0.f, 0.f};
    float m = -INFINITY, l = 0.f;

    const int srow = lane >> 3;          // 0..7
    const int slot = lane & 7;
    const int sw8 = (slot ^ srow) * 8;   // pre-swizzled 16B slot

    const short* kcol = qkvb + (size_t)b * TSEQ * (3 * DIMX) + DIMX + h * DKH;
    const short* vrow = vt + (size_t)bh * DKH * TSEQ;

    const int ntiles = j + 1;

#define STAGE(BUF, TIX)                                                        \
    {                                                                          \
        const int s0_ = (TIX) * 64;                                            \
        _Pragma("unroll")                                                      \
        for (int iss = 0; iss < 2; ++iss) {                                    \
            const int rb = 8 * w + 32 * iss;                                   \
            const short* ksrc = kcol + (size_t)(s0_ + rb + srow) * (3 * DIMX) + sw8; \
            const short* vsrc = vrow + (size_t)(rb + srow) * TSEQ + s0_ + sw8; \
            __builtin_amdgcn_global_load_lds(                                  \
                (const __attribute__((address_space(1))) void*)ksrc,           \
                (__attribute__((address_space(3))) void*)((char*)&Ks[BUF][0] + rb * 128), 16, 0, 0); \
            __builtin_amdgcn_global_load_lds(                                  \
                (const __attribute__((address_space(1))) void*)vsrc,           \
                (__attribute__((address_space(3))) void*)((char*)&Vs[BUF][0] + rb * 128), 16, 0, 0); \
        }                                                                      \
    }

    STAGE(0, 0)
    asm volatile("s_waitcnt vmcnt(0)" ::: "memory");
    __builtin_amdgcn_s_barrier();

    for (int tix = 0; tix < ntiles; ++tix) {
        const int cur = tix & 1;
        if (tix + 1 < ntiles) STAGE(cur ^ 1, tix + 1)   // prefetch next tile
        const int s0 = tix * 64;
        const short* Kb = &Ks[cur][0];
        const short* Vb = &Vs[cur][0];

        // swapped QK^T: SF[f] covers s-block [16f,16f+16); lane: s=16f+4g+i, col q
        f32x4 SF[4];
#pragma unroll
        for (int f = 0; f < 4; ++f) SF[f] = f32x4{0.f, 0.f, 0.f, 0.f};
        __builtin_amdgcn_s_setprio(1);
#pragma unroll
        for (int f = 0; f < 4; ++f) {
            const int rx = (16 * f + q) * 64;
            const int r7 = q & 7;
#pragma unroll
            for (int kd = 0; kd < 2; ++kd) {
                short8 kf = *(const short8*)&Kb[rx + (((kd << 2) + g) ^ r7) * 8];
                SF[f] = __builtin_amdgcn_mfma_f32_16x16x32_bf16(kf, QF[kd], SF[f], 0, 0, 0);
            }
        }
        __builtin_amdgcn_s_setprio(0);

        attn_process_qb(SF, OF, m, l, Vb, s0, trow, tix == ntiles - 1, g, q);

        asm volatile("s_waitcnt vmcnt(0)" ::: "memory");
        __builtin_amdgcn_s_barrier();
    }
#undef STAGE

    // epilogue: O^T[d][q] / l  ->  ctx[b*T + trow][h*64 + d]
    const float inv = 1.f / l;
#pragma unroll
    for (int db = 0; db < 4; ++db) {
        uint2v o;
        o.x = pack2bf(OF[db][0] * inv, OF[db][1] * inv);
        o.y = pack2bf(OF[db][2] * inv, OF[db][3] * inv);
        *(uint2v*)(ctx + ((size_t)b * TSEQ + trow) * DIMX + h * DKH + db * 16 + g * 4) = o;
    }
}

// ---------------------------------------------------------------------------
// Fused residual + LayerNorm: out = LN(resid + y)*g + b  (fp32 + bf16 outputs)
// ---------------------------------------------------------------------------
__global__ __launch_bounds__(256) void ln_kernel(const float* __restrict__ resid,
                                                 const float* __restrict__ y,
                                                 const float* __restrict__ g,
                                                 const float* __restrict__ bta,
                                                 float* __restrict__ out,
                                                 short* __restrict__ outb) {
    const int row = blockIdx.x;
    const int tid = threadIdx.x;
    __shared__ float red[4];

    float v[3];
#pragma unroll
    for (int i = 0; i < 3; i++) {
        int idx = tid + i * 256;
        size_t p = (size_t)row * DIMX + idx;
        v[i] = resid[p] + y[p];
    }
    float part = v[0] + v[1] + v[2];
#pragma unroll
    for (int off = 32; off; off >>= 1) part += __shfl_xor(part, off, 64);
    if ((tid & 63) == 0) red[tid >> 6] = part;
    __syncthreads();
    const float mean = (red[0] + red[1] + red[2] + red[3]) * (1.f / 768.f);

    float p2 = 0.f;
#pragma unroll
    for (int i = 0; i < 3; i++) {
        float d = v[i] - mean;
        p2 += d * d;
    }
#pragma unroll
    for (int off = 32; off; off >>= 1) p2 += __shfl_xor(p2, off, 64);
    __syncthreads();
    if ((tid & 63) == 0) red[tid >> 6] = p2;
    __syncthreads();
    const float var = (red[0] + red[1] + red[2] + red[3]) * (1.f / 768.f);
    const float inv = rsqrtf(var + 1e-5f);

#pragma unroll
    for (int i = 0; i < 3; i++) {
        int idx = tid + i * 256;
        float r = (v[i] - mean) * inv * g[idx] + bta[idx];
        out[(size_t)row * DIMX + idx] = r;
        outb[(size_t)row * DIMX + idx] = f2bf(r);
    }
}

// ---------------------------------------------------------------------------
extern "C" void kernel_launch(void* const* d_in, const int* in_sizes, int n_in,
                              void* d_out, int out_size, void* d_ws, size_t ws_size,
                              hipStream_t stream) {
    (void)in_sizes; (void)n_in; (void)out_size; (void)ws_size;
    const float* x     = (const float*)d_in[0];
    const float* qkv_w = (const float*)d_in[2];
    const float* qkv_b = (const float*)d_in[3];
    const float* out_w = (const float*)d_in[4];
    const float* out_b = (const float*)d_in[5];
    const float* ff1_w = (const float*)d_in[6];
    const float* ff1_b = (const float*)d_in[7];
    const float* ff2_w = (const float*)d_in[8];
    const float* ff2_b = (const float*)d_in[9];
    const float* ln1_g = (const float*)d_in[10];
    const float* ln1_b = (const float*)d_in[11];
    const float* ln2_g = (const float*)d_in[12];
    const float* ln2_b = (const float*)d_in[13];

    // ws layout
    char* p = (char*)d_ws;
    float* h      = (float*)p;  p += (size_t)MROWS * DIMX * 4;
    float* y      = (float*)p;  p += (size_t)MROWS * DIMX * 4;
    short* h_bf   = (short*)p;  p += (size_t)MROWS * DIMX * 2;
    short* ctx_bf = (short*)p;  p += (size_t)MROWS * DIMX * 2;
    short* ff_bf  = (short*)p;  p += (size_t)MROWS * FFDIM * 2;
    short* qkv_bf = (short*)p;  p += (size_t)MROWS * 3 * DIMX * 2;
    short* vtb    = (short*)p;  p += (size_t)NBH * DKH * TSEQ * 2;
    short* qkvT   = (short*)p;  p += (size_t)DEPTH * 3 * DIMX * DIMX * 2;
    short* outT   = (short*)p;  p += (size_t)DEPTH * DIMX * DIMX * 2;
    short* ff1T   = (short*)p;  p += (size_t)DEPTH * FFDIM * DIMX * 2;
    short* ff2T   = (short*)p;  p += (size_t)DEPTH * DIMX * FFDIM * 2;

    for (int l = 0; l < DEPTH; ++l) {
        wt_kernel<<<dim3(3 * DIMX / 32, DIMX / 32), 256, 0, stream>>>(
            qkv_w + (size_t)l * DIMX * 3 * DIMX, qkvT + (size_t)l * 3 * DIMX * DIMX,
            DIMX, 3 * DIMX);
        wt_kernel<<<dim3(DIMX / 32, DIMX / 32), 256, 0, stream>>>(
            out_w + (size_t)l * DIMX * DIMX, outT + (size_t)l * DIMX * DIMX,
            DIMX, DIMX);
        wt_kernel<<<dim3(FFDIM / 32, DIMX / 32), 256, 0, stream>>>(
            ff1_w + (size_t)l * DIMX * FFDIM, ff1T + (size_t)l * FFDIM * DIMX,
            DIMX, FFDIM);
        wt_kernel<<<dim3(DIMX / 32, FFDIM / 32), 256, 0, stream>>>(
            ff2_w + (size_t)l * FFDIM * DIMX, ff2T + (size_t)l * DIMX * FFDIM,
            FFDIM, DIMX);
    }

    pe_add_kernel<<<(MROWS * DIMX + 255) / 256, 256, 0, stream>>>(x, h, h_bf);

    for (int l = 0; l < DEPTH; ++l) {
        gemm_bf16_kernel<0, 1><<<dim3(3 * DIMX / 128, MROWS / 128), 256, 0, stream>>>(
            h_bf, qkvT + (size_t)l * 3 * DIMX * DIMX, qkv_b + (size_t)l * 3 * DIMX,
            nullptr, qkv_bf, MROWS, 3 * DIMX, DIMX);
        vt_kernel<<<NBH * (TSEQ / 64), 256, 0, stream>>>(qkv_bf, vtb);
        attn_mfma_kernel<<<NBH * 32, 256, 0, stream>>>(qkv_bf, vtb, ctx_bf);
        gemm_bf16_kernel<0, 0><<<dim3(DIMX / 128, MROWS / 128), 256, 0, stream>>>(
            ctx_bf, outT + (size_t)l * DIMX * DIMX, out_b + (size_t)l * DIMX,
            y, nullptr, MROWS, DIMX, DIMX);
        ln_kernel<<<MROWS, 256, 0, stream>>>(h, y, ln1_g + (size_t)l * DIMX,
                                             ln1_b + (size_t)l * DIMX, h, h_bf);
        gemm_bf16_kernel<1, 1><<<dim3(FFDIM / 128, MROWS / 128), 256, 0, stream>>>(
            h_bf, ff1T + (size_t)l * FFDIM * DIMX, ff1_b + (size_t)l * FFDIM,
            nullptr, ff_bf, MROWS, FFDIM, DIMX);
        gemm_bf16_kernel<0, 0><<<dim3(DIMX / 128, MROWS / 128), 256, 0, stream>>>(
            ff_bf, ff2T + (size_t)l * DIMX * FFDIM, ff2_b + (size_t)l * DIMX,
            y, nullptr, MROWS, DIMX, FFDIM);
        ln_kernel<<<MROWS, 256, 0, stream>>>(h, y, ln2_g + (size_t)l * DIMX,
                                             ln2_b + (size_t)l * DIMX, h, h_bf);
    }
    hipMemcpyAsync(d_out, h, (size_t)MROWS * DIMX * sizeof(float),
                   hipMemcpyDeviceToDevice, stream);
}